// Round 4
// baseline (5003.998 us; speedup 1.0000x reference)
//
#include <hip/hip_runtime.h>
#include <hip/hip_bf16.h>
#include <stdint.h>

// Problem: B=32, P=12, N=512, F=64, D=256, Q=12, DT=0.1
// Outputs: out1 = mgt (B,Q,N,F) fp32 ; out2 = kalman mus (B,Q,N,F) fp32
// Kalman covariance/solve chain is dead code; mus[t] = Fm^(t+1) @ inputs[:, -1].
// Workspace is consumed adaptively: batch dim processed in chunks sized to ws_size.

__device__ __forceinline__ float bflo(uint32_t u){ union{uint32_t x;float f;}c; c.x=u<<16; return c.f; }
__device__ __forceinline__ float bfhi(uint32_t u){ union{uint32_t x;float f;}c; c.x=u&0xffff0000u; return c.f; }

// ---------------- kernel A: h2[b,q,n,d] = sum_p Tmix[p,q] * sum_f inp[b,p,n,f]*Win[f,d]  (bf16 out)
// inp/h2 pointers are pre-offset to the current batch chunk; b here is chunk-local.
__global__ __launch_bounds__(256) void k_h2(
    const float* __restrict__ inp, const float* __restrict__ Win,
    const float* __restrict__ Tmx, __hip_bfloat16* __restrict__ h2) {
  int b  = blockIdx.x >> 5;
  int n0 = (blockIdx.x & 31) << 4;   // 16 n-rows per block
  int t  = threadIdx.x;              // t = d (0..255)
  __shared__ float xs[12*16*64];     // [p][i][f] 48 KB
  __shared__ float tmx[144];
  float win[64];
  #pragma unroll
  for (int f = 0; f < 64; ++f) win[f] = Win[f*256 + t];
  if (t < 144) tmx[t] = Tmx[t];
  for (int u = t; u < 12*1024; u += 256) {
    int p = u >> 10, r = u & 1023;
    xs[u] = inp[(size_t)(b*12+p)*32768 + (size_t)n0*64 + r];
  }
  __syncthreads();
  for (int i = 0; i < 16; ++i) {
    float h1[12];
    #pragma unroll
    for (int p = 0; p < 12; ++p) {
      const float* xr = &xs[p*1024 + i*64];
      float acc = 0.f;
      #pragma unroll
      for (int f = 0; f < 64; f += 4) {
        float4 x4 = *(const float4*)&xr[f];
        acc += x4.x*win[f] + x4.y*win[f+1] + x4.z*win[f+2] + x4.w*win[f+3];
      }
      h1[p] = acc;
    }
    int n = n0 + i;
    #pragma unroll
    for (int q = 0; q < 12; ++q) {
      float acc = 0.f;
      #pragma unroll
      for (int p = 0; p < 12; ++p) acc += tmx[p*12+q]*h1[p];
      h2[(size_t)((b*12+q)*512 + n)*256 + t] = __float2bfloat16(acc);
    }
  }
}

// ---------------- kernel B: q/k/v = h2 @ {Wq,Wk,Wv}  (M=bc*12*512, K=256, N=256), bf16 out
__global__ __launch_bounds__(256) void k_qkv(
    const __hip_bfloat16* __restrict__ h2,
    const float* __restrict__ Wq, const float* __restrict__ Wk, const float* __restrict__ Wv,
    __hip_bfloat16* __restrict__ qb, __hip_bfloat16* __restrict__ kb, __hip_bfloat16* __restrict__ vb) {
  const float* W = (blockIdx.z==0) ? Wq : (blockIdx.z==1) ? Wk : Wv;
  __hip_bfloat16* out = (blockIdx.z==0) ? qb : (blockIdx.z==1) ? kb : vb;
  int m0 = blockIdx.x << 6;
  int n0 = blockIdx.y << 6;
  int t = threadIdx.x;
  int ty = t >> 4, tx = t & 15;
  __shared__ __align__(16) float as_t[32*68];  // [kk][row] transposed A tile
  __shared__ __align__(16) float bs[32*68];    // [kk][col]
  float acc[4][4] = {};
  for (int k0 = 0; k0 < 256; k0 += 32) {
    __syncthreads();
    const uint32_t* hsrc = reinterpret_cast<const uint32_t*>(h2 + (size_t)m0*256 + k0);
    for (int u = t; u < 1024; u += 256) {
      int r = u >> 4, c2 = (u & 15) << 1;
      uint32_t v = hsrc[(size_t)r*128 + (c2>>1)];
      as_t[c2*68 + r]     = bflo(v);
      as_t[(c2+1)*68 + r] = bfhi(v);
    }
    for (int u = t; u < 2048; u += 256) {
      int rr = u >> 6, cc = u & 63;
      bs[rr*68 + cc] = W[(k0+rr)*256 + n0 + cc];
    }
    __syncthreads();
    #pragma unroll
    for (int kk = 0; kk < 32; ++kk) {
      float4 a4 = *(const float4*)&as_t[kk*68 + (ty<<2)];
      float4 b4 = *(const float4*)&bs[kk*68 + (tx<<2)];
      acc[0][0] += a4.x*b4.x; acc[0][1] += a4.x*b4.y; acc[0][2] += a4.x*b4.z; acc[0][3] += a4.x*b4.w;
      acc[1][0] += a4.y*b4.x; acc[1][1] += a4.y*b4.y; acc[1][2] += a4.y*b4.z; acc[1][3] += a4.y*b4.w;
      acc[2][0] += a4.z*b4.x; acc[2][1] += a4.z*b4.y; acc[2][2] += a4.z*b4.z; acc[2][3] += a4.z*b4.w;
      acc[3][0] += a4.w*b4.x; acc[3][1] += a4.w*b4.y; acc[3][2] += a4.w*b4.z; acc[3][3] += a4.w*b4.w;
    }
  }
  #pragma unroll
  for (int ii = 0; ii < 4; ++ii) {
    __hip_bfloat16* orow = out + (size_t)(m0 + (ty<<2) + ii)*256 + n0 + (tx<<2);
    #pragma unroll
    for (int jj = 0; jj < 4; ++jj) orow[jj] = __float2bfloat16(acc[ii][jj]);
  }
}

// ---------------- kernel C: flash attention + residual + W_out epilogue -> out1 (fp32)
// h2/qb/kb/vb/out1 pre-offset to chunk; blockIdx.z = chunk-local b.
__global__ __launch_bounds__(256) void k_attn(
    const __hip_bfloat16* __restrict__ h2,
    const __hip_bfloat16* __restrict__ qb,
    const __hip_bfloat16* __restrict__ kb,
    const __hip_bfloat16* __restrict__ vb,
    const float* __restrict__ Wout,
    float* __restrict__ out1) {
  int n0 = blockIdx.x << 5;
  int qq = blockIdx.y;
  int b  = blockIdx.z;
  size_t base = (size_t)(b*12+qq) * (512*256);
  int t = threadIdx.x;
  int w = t >> 6, l = t & 63;
  int il = (w << 3) + (l & 7);
  int cg = l >> 3;
  // chunked layout: addr(j, c) = j*288 + (c>>5)*36 + (c&31)  -> conflict-free per-cg reads
  __shared__ __align__(16) float ks[32*288];
  __shared__ __align__(16) float vs[32*288];

  float qreg[32], o[32];
  {
    const uint4* q16 = reinterpret_cast<const uint4*>(qb + base + (size_t)(n0+il)*256 + cg*32);
    #pragma unroll
    for (int v = 0; v < 4; ++v) {
      uint4 u4 = q16[v];
      qreg[v*8+0]=bflo(u4.x)*0.0625f; qreg[v*8+1]=bfhi(u4.x)*0.0625f;
      qreg[v*8+2]=bflo(u4.y)*0.0625f; qreg[v*8+3]=bfhi(u4.y)*0.0625f;
      qreg[v*8+4]=bflo(u4.z)*0.0625f; qreg[v*8+5]=bfhi(u4.z)*0.0625f;
      qreg[v*8+6]=bflo(u4.w)*0.0625f; qreg[v*8+7]=bfhi(u4.w)*0.0625f;
    }
  }
  #pragma unroll
  for (int c = 0; c < 32; ++c) o[c] = 0.f;
  float m_i = -1e30f, l_i = 0.f;

  for (int m0 = 0; m0 < 512; m0 += 32) {
    __syncthreads();
    const uint4* ksrc = reinterpret_cast<const uint4*>(kb + base + (size_t)m0*256);
    const uint4* vsrc = reinterpret_cast<const uint4*>(vb + base + (size_t)m0*256);
    for (int u = t; u < 1024; u += 256) {
      int j = u >> 5;
      int c8 = (u & 31) << 3;
      int a0 = j*288 + ((c8 >> 5)*36) + (c8 & 31);
      uint4 kvx = ksrc[u];
      *(float4*)&ks[a0]   = make_float4(bflo(kvx.x), bfhi(kvx.x), bflo(kvx.y), bfhi(kvx.y));
      *(float4*)&ks[a0+4] = make_float4(bflo(kvx.z), bfhi(kvx.z), bflo(kvx.w), bfhi(kvx.w));
      uint4 vvx = vsrc[u];
      *(float4*)&vs[a0]   = make_float4(bflo(vvx.x), bfhi(vvx.x), bflo(vvx.y), bfhi(vvx.y));
      *(float4*)&vs[a0+4] = make_float4(bflo(vvx.z), bfhi(vvx.z), bflo(vvx.w), bfhi(vvx.w));
    }
    __syncthreads();

    // scores for 32 cols: partial dot over own 32-d chunk, xor-reduce over cg lanes
    float p[32];
    float mt = -1e30f;
    #pragma unroll
    for (int j = 0; j < 32; ++j) {
      const float* kr = &ks[j*288 + cg*36];
      float acc = 0.f;
      #pragma unroll
      for (int c = 0; c < 32; c += 4) {
        float4 k4 = *(const float4*)&kr[c];
        acc += qreg[c]*k4.x + qreg[c+1]*k4.y + qreg[c+2]*k4.z + qreg[c+3]*k4.w;
      }
      acc += __shfl_xor(acc, 8);
      acc += __shfl_xor(acc, 16);
      acc += __shfl_xor(acc, 32);
      p[j] = acc;
      mt = fmaxf(mt, acc);
    }
    // online softmax
    float mn = fmaxf(m_i, mt);
    float sc = __expf(m_i - mn);
    float rs = 0.f;
    #pragma unroll
    for (int j = 0; j < 32; ++j) { p[j] = __expf(p[j] - mn); rs += p[j]; }
    l_i = l_i*sc + rs;
    m_i = mn;
    #pragma unroll
    for (int c = 0; c < 32; ++c) o[c] *= sc;
    // PV accumulate into own d-chunk
    #pragma unroll
    for (int j = 0; j < 32; ++j) {
      const float* vr = &vs[j*288 + cg*36];
      float pj = p[j];
      #pragma unroll
      for (int c = 0; c < 32; c += 4) {
        float4 v4 = *(const float4*)&vr[c];
        o[c] += pj*v4.x; o[c+1] += pj*v4.y; o[c+2] += pj*v4.z; o[c+3] += pj*v4.w;
      }
    }
  }

  // epilogue: h = h2 + attn@v ; out = h @ Wout
  float inv = 1.f / l_i;
  float hrow[32];
  {
    const uint4* h16 = reinterpret_cast<const uint4*>(h2 + base + (size_t)(n0+il)*256 + cg*32);
    #pragma unroll
    for (int v = 0; v < 4; ++v) {
      uint4 u4 = h16[v];
      hrow[v*8+0]=bflo(u4.x); hrow[v*8+1]=bfhi(u4.x);
      hrow[v*8+2]=bflo(u4.y); hrow[v*8+3]=bfhi(u4.y);
      hrow[v*8+4]=bflo(u4.z); hrow[v*8+5]=bfhi(u4.z);
      hrow[v*8+6]=bflo(u4.w); hrow[v*8+7]=bfhi(u4.w);
    }
  }
  #pragma unroll
  for (int c = 0; c < 32; ++c) hrow[c] += o[c]*inv;
  __syncthreads();                       // all waves done reading ks/vs
  float* hs = ks;                        // reuse as [32][260]
  #pragma unroll
  for (int c = 0; c < 32; ++c) hs[il*260 + cg*32 + c] = hrow[c];
  __syncthreads();
  float* wsml = vs;                      // reuse as [64][68]
  int i2 = t >> 4;
  int f0 = (t & 15) << 2;
  float aa0=0,aa1=0,aa2=0,aa3=0, ba0=0,ba1=0,ba2=0,ba3=0;
  for (int c0 = 0; c0 < 256; c0 += 64) {
    for (int u = t; u < 4096; u += 256) {
      int cc = u >> 6, f = u & 63;
      wsml[cc*68 + f] = Wout[(c0+cc)*64 + f];
    }
    __syncthreads();
    #pragma unroll 8
    for (int cc = 0; cc < 64; ++cc) {
      float ha = hs[i2*260 + c0 + cc];
      float hb = hs[(i2+16)*260 + c0 + cc];
      float4 w4 = *(const float4*)&wsml[cc*68 + f0];
      aa0 += ha*w4.x; aa1 += ha*w4.y; aa2 += ha*w4.z; aa3 += ha*w4.w;
      ba0 += hb*w4.x; ba1 += hb*w4.y; ba2 += hb*w4.z; ba3 += hb*w4.w;
    }
    __syncthreads();
  }
  float* dst = out1 + ((size_t)(b*12+qq)*512 + (n0+i2))*64 + f0;
  *(float4*)dst = make_float4(aa0,aa1,aa2,aa3);
  *(float4*)(dst + 16*64) = make_float4(ba0,ba1,ba2,ba3);
}

// ---------------- kalman: Fm = I + DT*A, then mu_t = Fm @ mu_{t-1} (12 chained batched GEMMs)
__global__ void k_fm(const float* __restrict__ A, float* __restrict__ Fm) {
  int idx = blockIdx.x*256 + threadIdx.x;
  int r = idx >> 9, c = idx & 511;
  Fm[idx] = 0.1f*A[idx] + ((r==c) ? 1.f : 0.f);
}

__global__ __launch_bounds__(256) void k_kal(
    const float* __restrict__ Fm, const float* __restrict__ prev, float* __restrict__ dst) {
  int n0 = blockIdx.x << 5;   // 32 output rows per block
  int b  = blockIdx.y;
  const float* P = prev + (size_t)b*393216;   // b-stride = 12*512*64 for both inputs-slice and out2
  float* Dp = dst + (size_t)b*393216;
  int t = threadIdx.x;
  int ty = t >> 4, tx = t & 15;
  __shared__ __align__(16) float as_t[32*36];  // Fm tile transposed [kk][r]
  __shared__ __align__(16) float bs[32*68];    // P tile [kk][f]
  float a0_[4]={0,0,0,0}, a1_[4]={0,0,0,0};
  for (int m0 = 0; m0 < 512; m0 += 32) {
    __syncthreads();
    for (int u = t; u < 1024; u += 256) {
      int r = u >> 5, c = u & 31;
      as_t[c*36 + r] = Fm[(size_t)(n0+r)*512 + m0 + c];
    }
    for (int u = t; u < 2048; u += 256) {
      int kk = u >> 6, f = u & 63;
      bs[kk*68 + f] = P[(size_t)(m0+kk)*64 + f];
    }
    __syncthreads();
    #pragma unroll
    for (int kk = 0; kk < 32; ++kk) {
      float2 a2 = *(const float2*)&as_t[kk*36 + (ty<<1)];
      float4 b4 = *(const float4*)&bs[kk*68 + (tx<<2)];
      a0_[0] += a2.x*b4.x; a0_[1] += a2.x*b4.y; a0_[2] += a2.x*b4.z; a0_[3] += a2.x*b4.w;
      a1_[0] += a2.y*b4.x; a1_[1] += a2.y*b4.y; a1_[2] += a2.y*b4.z; a1_[3] += a2.y*b4.w;
    }
  }
  float* d0 = &Dp[(size_t)(n0 + (ty<<1))*64 + (tx<<2)];
  *(float4*)d0      = make_float4(a0_[0],a0_[1],a0_[2],a0_[3]);
  *(float4*)(d0+64) = make_float4(a1_[0],a1_[1],a1_[2],a1_[3]);
}

extern "C" void kernel_launch(void* const* d_in, const int* in_sizes, int n_in,
                              void* d_out, int out_size, void* d_ws, size_t ws_size,
                              hipStream_t stream) {
  const float* inp  = (const float*)d_in[0];
  // d_in[1] = targets (unused by reference)
  const float* Win  = (const float*)d_in[2];
  const float* Tmx  = (const float*)d_in[3];
  const float* Wq   = (const float*)d_in[4];
  const float* Wk   = (const float*)d_in[5];
  const float* Wv   = (const float*)d_in[6];
  const float* Wout = (const float*)d_in[7];
  const float* A    = (const float*)d_in[8];
  // q_noise, r_noise unused (dead covariance chain)

  float* out1 = (float*)d_out;               // mgt (32,12,512,64)
  float* out2 = out1 + 12582912;             // kalman (32,12,512,64)

  // ---- workspace budget (adaptive to ws_size) ----
  // head: Fm (512*512 fp32 = 1 MB, padded to 1 MiB). Then per-batch chunk:
  // 4 bf16 buffers (h2,q,k,v) x 12*512*256 elements = 12,582,912 B per batch.
  const size_t FM_RESERVE = 1 << 20;
  const size_t perBatchElems = (size_t)12*512*256;       // per buffer, per batch
  const size_t perBatchBytes = 4 * perBatchElems * 2;    // 12.58 MB
  float* Fm = (float*)d_ws;
  char* chunkBase = (char*)d_ws + FM_RESERVE;
  size_t avail = (ws_size > FM_RESERVE) ? ws_size - FM_RESERVE : 0;
  int bchunk = (int)(avail / perBatchBytes);
  if (bchunk > 32) bchunk = 32;
  if (bchunk < 1)  bchunk = 1;   // last resort; needs ~13.6 MB of ws

  // Kalman rollout (independent of MGT; launch first so it overlaps chunk 0 staging)
  k_fm <<<dim3(1024), dim3(256), 0, stream>>>(A, Fm);
  const float* prev = inp + 11*32768;        // inputs[:, P-1] slice (b-stride 393216)
  for (int t = 0; t < 12; ++t) {
    k_kal<<<dim3(16, 32), dim3(256), 0, stream>>>(Fm, prev, out2 + (size_t)t*32768);
    prev = out2 + (size_t)t*32768;
  }

  // MGT pipeline, chunked over batches
  for (int b0 = 0; b0 < 32; b0 += bchunk) {
    int bc = (b0 + bchunk <= 32) ? bchunk : (32 - b0);
    size_t chunkElems = (size_t)bc * perBatchElems;
    __hip_bfloat16* h2 = (__hip_bfloat16*)chunkBase;
    __hip_bfloat16* qb = h2 + chunkElems;
    __hip_bfloat16* kb = qb + chunkElems;
    __hip_bfloat16* vb = kb + chunkElems;
    const float* inpC = inp + (size_t)b0*393216;
    float* out1C = out1 + (size_t)b0*393216;

    k_h2 <<<dim3(bc*32),          dim3(256), 0, stream>>>(inpC, Win, Tmx, h2);
    k_qkv<<<dim3(bc*96, 4, 3),    dim3(256), 0, stream>>>(h2, Wq, Wk, Wv, qb, kb, vb);
    k_attn<<<dim3(16, 12, bc),    dim3(256), 0, stream>>>(h2, qb, kb, vb, Wout, out1C);
  }
}